// Round 5
// baseline (307.113 us; speedup 1.0000x reference)
//
#include <hip/hip_runtime.h>

#define L_ 1024
#define DM 1024

typedef float f32x4 __attribute__((ext_vector_type(4)));
typedef _Float16 f16;
typedef _Float16 f16x8 __attribute__((ext_vector_type(8)));
typedef _Float16 f16x4 __attribute__((ext_vector_type(4)));
typedef _Float16 f16x2 __attribute__((ext_vector_type(2)));

__device__ __forceinline__ void gload16(const void* g, void* l) {
  __builtin_amdgcn_global_load_lds(
      (const __attribute__((address_space(1))) unsigned int*)g,
      (__attribute__((address_space(3))) unsigned int*)l, 16, 0, 0);
}

// cvt_pkrtz returns __fp16x2; bit_cast to our f16x2
__device__ __forceinline__ f16x2 pkrtz(float a, float b) {
  return __builtin_bit_cast(f16x2, __builtin_amdgcn_cvt_pkrtz(a, b));
}

#if __has_builtin(__builtin_amdgcn_fdot2)
__device__ __forceinline__ float DOT2(f16x2 a, f16x2 b, float c) {
  return __builtin_amdgcn_fdot2(__builtin_bit_cast(__fp16 __attribute__((ext_vector_type(2))), a),
                                __builtin_bit_cast(__fp16 __attribute__((ext_vector_type(2))), b),
                                c, false);
}
#else
__device__ __forceinline__ float DOT2(f16x2 a, f16x2 b, float c) {
  return fmaf((float)a[0], (float)b[0], fmaf((float)a[1], (float)b[1], c));
}
#endif

// ---------------- all f32->f16 conversions in one launch ----------------
__global__ __launch_bounds__(256) void cvt_all(const float* __restrict__ q,
    const float* __restrict__ k, const float* __restrict__ v,
    const float* __restrict__ wq, const float* __restrict__ wk,
    const float* __restrict__ wv, const float* __restrict__ wo,
    f16* __restrict__ dbig, f16* __restrict__ dw, f16* __restrict__ dwo) {
  int i = blockIdx.x * 256 + threadIdx.x;  // 8-elem units, 2097152 total
  const float* s; f16* d; int off;
  if (i < 524288)       { s = q;  d = dbig;           off = i; }
  else if (i < 1048576) { s = k;  d = dbig + 4194304; off = i - 524288; }
  else if (i < 1572864) { s = v;  d = dbig + 8388608; off = i - 1048576; }
  else if (i < 1703936) { s = wq; d = dw;             off = i - 1572864; }
  else if (i < 1835008) { s = wk; d = dw + 1048576;   off = i - 1703936; }
  else if (i < 1966080) { s = wv; d = dw + 2097152;   off = i - 1835008; }
  else                  { s = wo; d = dwo;            off = i - 1966080; }
  const float4* sp = (const float4*)s + (size_t)off * 2;
  float4 a = sp[0], bb = sp[1];
  f16x8 o;
  o[0] = (f16)a.x;  o[1] = (f16)a.y;  o[2] = (f16)a.z;  o[3] = (f16)a.w;
  o[4] = (f16)bb.x; o[5] = (f16)bb.y; o[6] = (f16)bb.z; o[7] = (f16)bb.w;
  ((f16x8*)d)[off] = o;
}

__global__ __launch_bounds__(256) void biascat(const float* __restrict__ bq,
    const float* __restrict__ bk, const float* __restrict__ bv, float* __restrict__ o) {
  int t = blockIdx.x * 256 + threadIdx.x;  // 3072
  o[t] = (t < 1024) ? bq[t] : (t < 2048) ? bk[t - 1024] : bv[t - 2048];
}

// ---------------- QKV projection, z-batched, global_load_lds staging ----------------
__global__ __launch_bounds__(256) void proj_gemm(const f16* __restrict__ Ain,
    const f16* __restrict__ Wc, const float* __restrict__ bcat, f16* __restrict__ QKVp) {
  alignas(16) __shared__ f16 At[128 * 32];
  alignas(16) __shared__ f16 Bt[128 * 32];
  int z = blockIdx.z;
  const f16* A = Ain + (size_t)z * 4194304;
  const f16* W = Wc + (size_t)z * 1048576;
  int t = threadIdx.x, lane = t & 63;
  int w = t >> 6, wr = w >> 1, wc = w & 1;
  int bm = blockIdx.y * 128, bn = blockIdx.x * 128;
  f32x4 acc[4][4] = {};
  int rb = 32 * w + (lane >> 2);
  int c8 = (lane & 3) * 8;
  const f16* gA = A + (size_t)(bm + rb) * 1024 + c8;
  const f16* gB = W + (size_t)(bn + rb) * 1024 + c8;
  f16* lA0 = &At[(2 * w) * 512];
  f16* lA1 = &At[(2 * w + 1) * 512];
  f16* lB0 = &Bt[(2 * w) * 512];
  f16* lB1 = &Bt[(2 * w + 1) * 512];
  int ro = (lane & 15) * 32 + (lane >> 4) * 8;
  for (int kk = 0; kk < 1024; kk += 32) {
    gload16(gA + kk, lA0);
    gload16(gA + 16 * 1024 + kk, lA1);
    gload16(gB + kk, lB0);
    gload16(gB + 16 * 1024 + kk, lB1);
    __syncthreads();
    f16x8 af[4], bf[4];
    #pragma unroll
    for (int m = 0; m < 4; ++m) af[m] = *(const f16x8*)&At[(wr * 64 + m * 16) * 32 + ro];
    #pragma unroll
    for (int n = 0; n < 4; ++n) bf[n] = *(const f16x8*)&Bt[(wc * 64 + n * 16) * 32 + ro];
    #pragma unroll
    for (int m = 0; m < 4; ++m)
      #pragma unroll
      for (int n = 0; n < 4; ++n)
        acc[m][n] = __builtin_amdgcn_mfma_f32_16x16x32_f16(af[m], bf[n], acc[m][n], 0, 0, 0);
    __syncthreads();
  }
  float scale = (z == 0) ? 0.125f : 1.0f;
  #pragma unroll
  for (int n = 0; n < 4; ++n) {
    int cn = bn + wc * 64 + n * 16 + (lane & 15);
    float bvv = bcat[z * 1024 + cn];
    #pragma unroll
    for (int m = 0; m < 4; ++m) {
      int r0 = bm + wr * 64 + m * 16 + (lane >> 4) * 4;
      #pragma unroll
      for (int r = 0; r < 4; ++r)
        QKVp[(size_t)(r0 + r) * 3072 + z * 1024 + cn] = (f16)((acc[m][n][r] + bvv) * scale);
    }
  }
}

// ---------------- output projection (f32 out) ----------------
__global__ __launch_bounds__(256) void gemm_out(const f16* __restrict__ A,
    const f16* __restrict__ W, const float* __restrict__ bias, float* __restrict__ C) {
  alignas(16) __shared__ f16 At[128 * 32];
  alignas(16) __shared__ f16 Bt[128 * 32];
  int t = threadIdx.x, lane = t & 63;
  int w = t >> 6, wr = w >> 1, wc = w & 1;
  int bm = blockIdx.y * 128, bn = blockIdx.x * 128;
  f32x4 acc[4][4] = {};
  int rb = 32 * w + (lane >> 2);
  int c8 = (lane & 3) * 8;
  const f16* gA = A + (size_t)(bm + rb) * 1024 + c8;
  const f16* gB = W + (size_t)(bn + rb) * 1024 + c8;
  f16* lA0 = &At[(2 * w) * 512];
  f16* lA1 = &At[(2 * w + 1) * 512];
  f16* lB0 = &Bt[(2 * w) * 512];
  f16* lB1 = &Bt[(2 * w + 1) * 512];
  int ro = (lane & 15) * 32 + (lane >> 4) * 8;
  for (int kk = 0; kk < 1024; kk += 32) {
    gload16(gA + kk, lA0);
    gload16(gA + 16 * 1024 + kk, lA1);
    gload16(gB + kk, lB0);
    gload16(gB + 16 * 1024 + kk, lB1);
    __syncthreads();
    f16x8 af[4], bf[4];
    #pragma unroll
    for (int m = 0; m < 4; ++m) af[m] = *(const f16x8*)&At[(wr * 64 + m * 16) * 32 + ro];
    #pragma unroll
    for (int n = 0; n < 4; ++n) bf[n] = *(const f16x8*)&Bt[(wc * 64 + n * 16) * 32 + ro];
    #pragma unroll
    for (int m = 0; m < 4; ++m)
      #pragma unroll
      for (int n = 0; n < 4; ++n)
        acc[m][n] = __builtin_amdgcn_mfma_f32_16x16x32_f16(af[m], bf[n], acc[m][n], 0, 0, 0);
    __syncthreads();
  }
  #pragma unroll
  for (int n = 0; n < 4; ++n) {
    int cn = bn + wc * 64 + n * 16 + (lane & 15);
    float bvv = bias[cn];
    #pragma unroll
    for (int m = 0; m < 4; ++m) {
      int r0 = bm + wr * 64 + m * 16 + (lane >> 4) * 4;
      #pragma unroll
      for (int r = 0; r < 4; ++r)
        C[(size_t)(r0 + r) * 1024 + cn] = acc[m][n][r] + bvv;
    }
  }
}

// ---------------- V section of QKVp -> Vt [(b*16+h)*64 + d][k] ----------------
__global__ __launch_bounds__(256) void transpose_v(const f16* __restrict__ QKVp,
                                                   f16* __restrict__ Vt) {
  alignas(16) __shared__ f16 T[64 * 72];
  int bh = blockIdx.y;
  int b = bh >> 4, h = bh & 15;
  int kt = blockIdx.x;
  int t = threadIdx.x;
  int krow = t >> 2, part = t & 3;
  const f16x8* src = (const f16x8*)(QKVp + (size_t)(b * L_ + kt * 64 + krow) * 3072 + 2048 + h * 64 + part * 16);
  f16x8 v0 = src[0], v1 = src[1];
  *(f16x8*)&T[krow * 72 + part * 16] = v0;
  *(f16x8*)&T[krow * 72 + part * 16 + 8] = v1;
  __syncthreads();
  int drow = t >> 2;
  f16x8 o0, o1;
  #pragma unroll
  for (int j = 0; j < 8; ++j) o0[j] = T[(part * 16 + j) * 72 + drow];
  #pragma unroll
  for (int j = 0; j < 8; ++j) o1[j] = T[(part * 16 + 8 + j) * 72 + drow];
  f16* dst = Vt + (size_t)(bh * 64 + drow) * L_ + kt * 64 + part * 16;
  *(f16x8*)dst = o0;
  *(f16x8*)(dst + 8) = o1;
}

// ---------------- cb[b][q][g] = sum_h attn_bias[b][h][q]*Wl[g][h] + bl[g] ----------------
__global__ __launch_bounds__(256) void cbias_kernel(const float* __restrict__ ab,
    const float* __restrict__ Wl, const float* __restrict__ bl, float* __restrict__ cb) {
  int t = blockIdx.x * 256 + threadIdx.x;  // 65536
  int b = t >> 14, q = (t >> 4) & 1023, g = t & 15;
  float s = bl[g];
  #pragma unroll
  for (int h = 0; h < 16; ++h) s += ab[(size_t)(b * 16 + h) * L_ + q] * Wl[g * 16 + h];
  cb[t] = s;
}

// ---------------- fused QK + mix1 + softmax(+ mix2 + w-write) ----------------
// grid 256: x=bid&7 -> XCD; b=x>>1; kqh=x&1; y=bid>>3: qt=y&15, kql=y>>4; kq=kqh*2+kql.
// Block: 4 waves x 16 q-rows, sweeping a 256-k slice in 16k tiles.
// WRITE_W=0: accumulate exp-sum partials -> denomP[kq][q][g].
// WRITE_W=1: recompute logits identically, P=E*rl, mix2 -> w[h][q][k] (global).
template <int WRITE_W>
__global__ __launch_bounds__(256, 1) void attn_ab(const f16* __restrict__ QKVp,
    const float* __restrict__ Wl, const float* __restrict__ Ww, const float* __restrict__ bwv,
    const float* __restrict__ cbp, const float* __restrict__ rlp,
    float* __restrict__ denomP, f16* __restrict__ wG) {
  alignas(16) __shared__ f16 Kl[2][16][1032];
  __shared__ f16x2 wlp[16][8];  // [g][h-pair]
  int bid = blockIdx.x;
  int x = bid & 7, y = bid >> 3;
  int b = x >> 1, qt = y & 15, kq = ((x & 1) << 1) | (y >> 4);
  int t = threadIdx.x, lane = t & 63, wv = t >> 6;
  int l15 = lane & 15, lhi = lane >> 4;
  if (t < 128) {
    int g = t >> 3, p = t & 7;
    wlp[g][p] = pkrtz(Wl[g * 16 + 2 * p], Wl[g * 16 + 2 * p + 1]);
  }
  int qg = b * 1024 + qt * 64 + wv * 16 + l15;  // this lane's q row (global)
  // Q fragments in registers: qf[h][s] = Q[qg][h*64 + s*32 + lhi*8 ..+7]
  f16x8 qf[16][2];
  #pragma unroll
  for (int h = 0; h < 16; ++h)
    #pragma unroll
    for (int s = 0; s < 2; ++s)
      qf[h][s] = *(const f16x8*)(QKVp + (size_t)qg * 3072 + h * 64 + s * 32 + lhi * 8);
  float cbl[16];
  #pragma unroll
  for (int g4 = 0; g4 < 4; ++g4)
    *(f32x4*)&cbl[g4 * 4] = *(const f32x4*)(cbp + (size_t)qg * 16 + g4 * 4);
  float rlv[16];
  float dacc[16] = {};
  if constexpr (WRITE_W) {
    #pragma unroll
    for (int g4 = 0; g4 < 4; ++g4)
      *(f32x4*)&rlv[g4 * 4] = *(const f32x4*)(rlp + (size_t)qg * 16 + g4 * 4);
  }

  auto stage = [&](int nb, int it) {
    int k0 = b * 1024 + kq * 256 + it * 16;
    #pragma unroll
    for (int j = 0; j < 4; ++j) {
      int row = wv * 4 + j;
      const f16* src = QKVp + (size_t)(k0 + row) * 3072 + 1024 + lane * 8;
      gload16(src, &Kl[nb][row][0]);
      gload16(src + 512, &Kl[nb][row][512]);
    }
  };

  if constexpr (WRITE_W) {
    __shared__ f16x2 wwp[16][8];  // [h][g-pair]
    alignas(16) __shared__ f16 WT[16][64][20];
    if (t >= 128) {
      int h = (t - 128) >> 3, p = (t - 128) & 7;
      wwp[h][p] = pkrtz(Ww[h * 16 + 2 * p], Ww[h * 16 + 2 * p + 1]);
    }
    float bwl[16];
    #pragma unroll
    for (int h = 0; h < 16; ++h) bwl[h] = bwv[h];
    stage(0, 0);
    __syncthreads();
    for (int it = 0; it < 16; ++it) {
      int cur = it & 1;
      if (it < 15) stage(cur ^ 1, it + 1);
      f32x4 acc[16];
      #pragma unroll
      for (int h = 0; h < 16; ++h) {
        f16x8 a0 = *(const f16x8*)&Kl[cur][l15][h * 64 + lhi * 8];
        f16x8 a1 = *(const f16x8*)&Kl[cur][l15][h * 64 + 32 + lhi * 8];
        acc[h] = __builtin_amdgcn_mfma_f32_16x16x32_f16(a0, qf[h][0], (f32x4){0.f, 0.f, 0.f, 0.f}, 0, 0, 0);
        acc[h] = __builtin_amdgcn_mfma_f32_16x16x32_f16(a1, qf[h][1], acc[h], 0, 0, 0);
      }
      f16x2 sp[4][8];
      #pragma unroll
      for (int p = 0; p < 8; ++p)
        #pragma unroll
        for (int r = 0; r < 4; ++r)
          sp[r][p] = pkrtz(acc[2 * p][r], acc[2 * p + 1][r]);
      float E[4][16];
      #pragma unroll
      for (int g = 0; g < 16; ++g) {
        f16x2 wl[8];
        #pragma unroll
        for (int p = 0; p < 8; ++p) wl[p] = wlp[g][p];
        #pragma unroll
        for (int r = 0; r < 4; ++r) {
          float lg = cbl[g];
          #pragma unroll
          for (int p = 0; p < 8; ++p) lg = DOT2(sp[r][p], wl[p], lg);
          E[r][g] = __expf(lg);
        }
      }
      f16x2 pp[4][8];
      #pragma unroll
      for (int r = 0; r < 4; ++r)
        #pragma unroll
        for (int p = 0; p < 8; ++p)
          pp[r][p] = pkrtz(E[r][2 * p] * rlv[2 * p], E[r][2 * p + 1] * rlv[2 * p + 1]);
      int wq = wv * 16 + l15;
      #pragma unroll
      for (int h = 0; h < 16; ++h) {
        f16x2 ww[8];
        #pragma unroll
        for (int p = 0; p < 8; ++p) ww[p] = wwp[h][p];
        float wr_[4];
        #pragma unroll
        for (int r = 0; r < 4; ++r) {
          float a = bwl[h];
          #pragma unroll
          for (int p = 0; p < 8; ++p) a = DOT2(pp[r][p], ww[p], a);
          wr_[r] = a;
        }
        f16x2 lo = pkrtz(wr_[0], wr_[1]);
        f16x2 hi = pkrtz(wr_[2], wr_[3]);
        f16x4 o; o[0] = lo[0]; o[1] = lo[1]; o[2] = hi[0]; o[3] = hi[1];
        *(f16x4*)&WT[h][wq][lhi * 4] = o;
      }
      __syncthreads();  // WT complete; next K tile resident
      #pragma unroll
      for (int i = 0; i < 4; ++i) {
        int rid = i * 256 + t;
        int h = rid >> 6, qq = rid & 63;
        const f16* srcw = &WT[h][qq][0];
        f16x4 v0 = *(const f16x4*)(srcw + 0), v1 = *(const f16x4*)(srcw + 4);
        f16x4 v2 = *(const f16x4*)(srcw + 8), v3 = *(const f16x4*)(srcw + 12);
        f16x8 o0, o1;
        #pragma unroll
        for (int j = 0; j < 4; ++j) { o0[j] = v0[j]; o0[j + 4] = v1[j]; o1[j] = v2[j]; o1[j + 4] = v3[j]; }
        f16* dst = wG + (size_t)(b * 16 + h) * 1048576 + (size_t)(qt * 64 + qq) * 1024 + kq * 256 + it * 16;
        *(f16x8*)dst = o0;
        *(f16x8*)(dst + 8) = o1;
      }
      __syncthreads();  // WT reusable
    }
  } else {
    stage(0, 0);
    __syncthreads();
    for (int it = 0; it < 16; ++it) {
      int cur = it & 1;
      if (it < 15) stage(cur ^ 1, it + 1);
      f32x4 acc[16];
      #pragma unroll
      for (int h = 0; h < 16; ++h) {
        f16x8 a0 = *(const f16x8*)&Kl[cur][l15][h * 64 + lhi * 8];
        f16x8 a1 = *(const f16x8*)&Kl[cur][l15][h * 64 + 32 + lhi * 8];
        acc[h] = __builtin_amdgcn_mfma_f32_16x16x32_f16(a0, qf[h][0], (f32x4){0.f, 0.f, 0.f, 0.f}, 0, 0, 0);
        acc[h] = __builtin_amdgcn_mfma_f32_16x16x32_f16(a1, qf[h][1], acc[h], 0, 0, 0);
      }
      f16x2 sp[4][8];
      #pragma unroll
      for (int p = 0; p < 8; ++p)
        #pragma unroll
        for (int r = 0; r < 4; ++r)
          sp[r][p] = pkrtz(acc[2 * p][r], acc[2 * p + 1][r]);
      #pragma unroll
      for (int g = 0; g < 16; ++g) {
        f16x2 wl[8];
        #pragma unroll
        for (int p = 0; p < 8; ++p) wl[p] = wlp[g][p];
        float e0 = 0.f, e1 = 0.f;
        #pragma unroll
        for (int r = 0; r < 4; ++r) {
          float lg = cbl[g];
          #pragma unroll
          for (int p = 0; p < 8; ++p) lg = DOT2(sp[r][p], wl[p], lg);
          if (r & 1) e1 += __expf(lg); else e0 += __expf(lg);
        }
        dacc[g] += e0 + e1;
      }
      __syncthreads();
    }
    // reduce over lhi groups (k sub-slots)
    #pragma unroll
    for (int g = 0; g < 16; ++g) {
      float v = dacc[g];
      v += __shfl_xor(v, 16);
      v += __shfl_xor(v, 32);
      dacc[g] = v;
    }
    if (lhi == 0) {
      float* dst = denomP + (size_t)kq * 65536 + (size_t)qg * 16;
      #pragma unroll
      for (int g4 = 0; g4 < 4; ++g4)
        *(f32x4*)(dst + g4 * 4) = *(const f32x4*)&dacc[g4 * 4];
    }
  }
}

__global__ __launch_bounds__(256) void combine_rl(const float* __restrict__ dp,
                                                  float* __restrict__ rl) {
  int i = blockIdx.x * 256 + threadIdx.x;  // 65536
  rl[i] = 1.0f / (dp[i] + dp[65536 + i] + dp[131072 + i] + dp[196608 + i]);
}

// ---------------- ctx[b*1024+q][h*64+d] = w[h][q][:] @ V[h][:][d]; grid (qt32, h16, b4) ----------------
__global__ __launch_bounds__(256) void pv_gemm(const f16* __restrict__ Sw,
    const f16* __restrict__ Vt, f16* __restrict__ ctx, int b0) {
  alignas(16) __shared__ f16 Aw[32 * 72];
  alignas(16) __shared__ f16 Bv[64 * 72];
  int t = threadIdx.x, lane = t & 63, w = t >> 6;
  int qt = blockIdx.x, h = blockIdx.y, bz = blockIdx.z;
  int wr = w >> 1, wc = w & 1;
  int l15 = lane & 15, lhi = lane >> 4;
  const f16* Sh = Sw + (size_t)(bz * 16 + h) * 1048576 + (size_t)(qt * 32) * 1024;
  const f16* Vh = Vt + (size_t)((b0 + bz) * 16 + h) * 64 * 1024;
  f32x4 acc[2] = {};
  int srow = t >> 3, scol = (t & 7) * 8;
  for (int kk = 0; kk < 1024; kk += 64) {
    __syncthreads();
    *(f16x8*)&Aw[srow * 72 + scol] = *(const f16x8*)(Sh + (size_t)srow * 1024 + kk + scol);
    *(f16x8*)&Bv[srow * 72 + scol] = *(const f16x8*)(Vh + (size_t)srow * 1024 + kk + scol);
    *(f16x8*)&Bv[(srow + 32) * 72 + scol] = *(const f16x8*)(Vh + (size_t)(srow + 32) * 1024 + kk + scol);
    __syncthreads();
    #pragma unroll
    for (int s = 0; s < 2; ++s) {
      f16x8 af = *(const f16x8*)&Aw[(wr * 16 + l15) * 72 + s * 32 + lhi * 8];
      #pragma unroll
      for (int n = 0; n < 2; ++n) {
        f16x8 bf = *(const f16x8*)&Bv[(wc * 32 + n * 16 + l15) * 72 + s * 32 + lhi * 8];
        acc[n] = __builtin_amdgcn_mfma_f32_16x16x32_f16(af, bf, acc[n], 0, 0, 0);
      }
    }
  }
  #pragma unroll
  for (int n = 0; n < 2; ++n) {
    int col = h * 64 + wc * 32 + n * 16 + l15;
    int q0 = (b0 + bz) * 1024 + qt * 32 + wr * 16 + lhi * 4;
    #pragma unroll
    for (int r = 0; r < 4; ++r)
      ctx[(size_t)(q0 + r) * 1024 + col] = (f16)acc[n][r];
  }
}

extern "C" void kernel_launch(void* const* d_in, const int* in_sizes, int n_in,
                              void* d_out, int out_size, void* d_ws, size_t ws_size,
                              hipStream_t stream) {
  const float* queries = (const float*)d_in[0];
  const float* keys    = (const float*)d_in[1];
  const float* values  = (const float*)d_in[2];
  const float* ab  = (const float*)d_in[4];
  const float* Wq  = (const float*)d_in[5];  const float* bq = (const float*)d_in[6];
  const float* Wk  = (const float*)d_in[7];  const float* bk = (const float*)d_in[8];
  const float* Wv  = (const float*)d_in[9];  const float* bv = (const float*)d_in[10];
  const float* Wl  = (const float*)d_in[11]; const float* bl = (const float*)d_in[12];
  const float* Ww  = (const float*)d_in[13]; const float* bwp = (const float*)d_in[14];
  const float* Wo  = (const float*)d_in[15]; const float* bo = (const float*)d_in[16];

  char* ws = (char*)d_ws;
  const size_t MB = 1024 * 1024;
  f16* qin   = (f16*)(ws + 0 * MB);        // 24 MB f16 inputs (dead after proj)
  f16* wqkv  = (f16*)(ws + 24 * MB);       // 6 MB (dead after proj)
  f16* wG    = (f16*)(ws + 0 * MB);        // 128 MB w tensor (written after proj)
  f16* QKVp  = (f16*)(ws + 128 * MB);      // 24 MB
  f16* Vt    = (f16*)(ws + 152 * MB);      // 8 MB
  f16* ctx   = (f16*)(ws + 160 * MB);      // 8 MB
  f16* wo16  = (f16*)(ws + 168 * MB);      // 2 MB
  float* cbp = (float*)(ws + 170 * MB);    // 256 KB
  float* rlp = (float*)(ws + 170 * MB + 256 * 1024);   // 256 KB
  float* dnp = (float*)(ws + 170 * MB + 512 * 1024);   // 1 MB
  float* bqkv = (float*)(ws + 171 * MB + 512 * 1024);  // 12 KB

  cvt_all<<<8192, 256, 0, stream>>>(queries, keys, values, Wq, Wk, Wv, Wo, qin, wqkv, wo16);
  biascat<<<12, 256, 0, stream>>>(bq, bk, bv, bqkv);
  proj_gemm<<<dim3(8, 32, 3), 256, 0, stream>>>(qin, wqkv, bqkv, QKVp);
  transpose_v<<<dim3(16, 64), 256, 0, stream>>>(QKVp, Vt);
  cbias_kernel<<<256, 256, 0, stream>>>(ab, Wl, bl, cbp);

  attn_ab<0><<<256, 256, 0, stream>>>(QKVp, Wl, Ww, bwp, cbp, rlp, dnp, wG);
  combine_rl<<<256, 256, 0, stream>>>(dnp, rlp);
  attn_ab<1><<<256, 256, 0, stream>>>(QKVp, Wl, Ww, bwp, cbp, rlp, dnp, wG);

  pv_gemm<<<dim3(32, 16, 4), 256, 0, stream>>>(wG, Vt, ctx, 0);
  gemm_out<<<dim3(8, 32), 256, 0, stream>>>(ctx, wo16, bo, (float*)d_out);
}